// Round 11
// baseline (203.502 us; speedup 1.0000x reference)
//
#include <hip/hip_runtime.h>
#include <hip/hip_fp16.h>

typedef _Float16 half8 __attribute__((ext_vector_type(8)));
typedef float f32x4 __attribute__((ext_vector_type(4)));

#define BUCKET_CAP 32768   // slots/bucket (1024-node buckets; mean 16327, sd 128)
#define BNODES 1024        // nodes per bucket
#define NBSHIFT 10

// ---------------------------------------------------------------- helpers

__device__ __forceinline__ unsigned pack_half2(float x, float y) {
    __half2 h = __float22half2_rn(make_float2(x, y));
    return *reinterpret_cast<unsigned*>(&h);
}
__device__ __forceinline__ float2 up2(unsigned u) {
    __half2 h = *reinterpret_cast<__half2*>(&u);
    return __half22float2(h);
}
__device__ __forceinline__ void acc8(float4& a, uint2 v) {
    float2 p = up2(v.x), q = up2(v.y);
    a.x += p.x; a.y += p.y; a.z += q.x; a.w += q.y;
}
__device__ __forceinline__ void acc4(float2& a, unsigned v) {
    float2 p = up2(v);
    a.x += p.x; a.y += p.y;
}
__device__ __forceinline__ uint2 ld8(const char* __restrict__ b, unsigned off) {
    return *reinterpret_cast<const uint2*>(b + off);
}
__device__ __forceinline__ unsigned ld4(const char* __restrict__ b, unsigned off) {
    return *reinterpret_cast<const unsigned*>(b + off);
}

// ---------------------------------------------------------------- fused init
// W1 [k][128] f32 -> Wt1 [col][k] f16 ; W2 [k][64] f32 -> Wt2 [col][k] f16
// + zero bcnt

__global__ __launch_bounds__(256) void k_wconv(const float* __restrict__ W1,
                                               const float* __restrict__ W2,
                                               __half* __restrict__ Wt1,
                                               __half* __restrict__ Wt2,
                                               int* __restrict__ bcnt, int nbz) {
    int i = blockIdx.x * 256 + threadIdx.x;
    if (i < nbz) bcnt[i] = 0;
    if (i < 16384) {
        int col = i >> 7, k = i & 127;
        Wt1[i] = __float2half(W1[(k << 7) + col]);
    } else if (i < 24576) {
        int j = i - 16384;
        int col = j >> 7, k = j & 127;
        Wt2[j] = __float2half(W2[(k << 6) + col]);
    }
}

// ------------------------------------------------ bucketed CSC construction
// Bucket = dst >> 10 (1024 nodes, NB = 98). Pairs in fixed-stride regions.
// Pair packed: src(17b) | dstLow10 << 17.

__global__ __launch_bounds__(256) void k_bscatter2(const int* __restrict__ src,
                                                   const int* __restrict__ dst, int E,
                                                   int* __restrict__ bcnt,
                                                   unsigned* __restrict__ pairs,
                                                   int NB, int epb) {
    __shared__ int h[128];
    __shared__ int base[128];
    for (int i = threadIdx.x; i < NB; i += 256) h[i] = 0;
    __syncthreads();
    int lo = blockIdx.x * epb;
    int hi = min(lo + epb, E);
    for (int e = lo + threadIdx.x; e < hi; e += 256)
        atomicAdd(&h[dst[e] >> NBSHIFT], 1);
    __syncthreads();
    for (int i = threadIdx.x; i < NB; i += 256) {
        int c = h[i];
        base[i] = c ? atomicAdd(&bcnt[i], c) : 0;
        h[i] = 0;  // becomes local cursor
    }
    __syncthreads();
    for (int e = lo + threadIdx.x; e < hi; e += 256) {
        int s = src[e], d = dst[e];
        int b = d >> NBSHIFT;
        int r = atomicAdd(&h[b], 1);
        pairs[(size_t)b * BUCKET_CAP + base[b] + r] =
            (unsigned)s | ((unsigned)(d & (BNODES - 1)) << 17);
    }
}

// per-bucket: bucket-base prefix over bcnt; 1024-bin hist -> dinv; blocked
// scan -> offs; csc placement.
__global__ __launch_bounds__(256) void k_bfinal2(const unsigned* __restrict__ pairs,
                                                 const int* __restrict__ bcnt,
                                                 float* __restrict__ dinv,
                                                 int* __restrict__ offs,
                                                 int* __restrict__ csc,
                                                 int n, int E, int NB) {
    __shared__ int cnt[BNODES];
    __shared__ int scn[256];
    __shared__ int cur[BNODES];
    int b = blockIdx.x, t = threadIdx.x;

    // bucket base = prefix sum of bcnt[0..b)
    int part = 0;
    for (int i = t; i < b; i += 256) part += bcnt[i];
    scn[t] = part;
    __syncthreads();
    for (int d = 128; d > 0; d >>= 1) {
        if (t < d) scn[t] += scn[t + d];
        __syncthreads();
    }
    int cbase = scn[0];
    int cnt_b = bcnt[b];
    __syncthreads();

    for (int i = t; i < BNODES; i += 256) cnt[i] = 0;
    __syncthreads();
    size_t plo = (size_t)b * BUCKET_CAP;
    for (int e = t; e < cnt_b; e += 256)
        atomicAdd(&cnt[pairs[plo + e] >> 17], 1);
    __syncthreads();

    // blocked scan: thread t owns nodes 4t..4t+3
    int c0 = cnt[4 * t], c1 = cnt[4 * t + 1], c2 = cnt[4 * t + 2], c3 = cnt[4 * t + 3];
    int tot = c0 + c1 + c2 + c3;
    __syncthreads();
    scn[t] = tot;
    __syncthreads();
    for (int d = 1; d < 256; d <<= 1) {
        int xv = (t >= d) ? scn[t - d] : 0;
        __syncthreads();
        scn[t] += xv;
        __syncthreads();
    }
    int basee = cbase + scn[t] - tot;
    int o0 = basee, o1 = basee + c0, o2 = o1 + c1, o3 = o2 + c2;
    int node0 = b * BNODES + 4 * t;
    if (node0 + 3 < n) {
        *reinterpret_cast<int4*>(offs + node0) = make_int4(o0, o1, o2, o3);
        *reinterpret_cast<float4*>(dinv + node0) =
            make_float4(rsqrtf((float)(c0 + 1)), rsqrtf((float)(c1 + 1)),
                        rsqrtf((float)(c2 + 1)), rsqrtf((float)(c3 + 1)));
    } else {
        if (node0 < n)     { offs[node0]     = o0; dinv[node0]     = rsqrtf((float)(c0 + 1)); }
        if (node0 + 1 < n) { offs[node0 + 1] = o1; dinv[node0 + 1] = rsqrtf((float)(c1 + 1)); }
        if (node0 + 2 < n) { offs[node0 + 2] = o2; dinv[node0 + 2] = rsqrtf((float)(c2 + 1)); }
    }
    if (b == NB - 1 && t == 255) offs[n] = E;
    cur[4 * t] = o0; cur[4 * t + 1] = o1; cur[4 * t + 2] = o2; cur[4 * t + 3] = o3;
    __syncthreads();
    for (int e = t; e < cnt_b; e += 256) {
        unsigned p = pairs[plo + e];
        int pos = atomicAdd(&cur[p >> 17], 1);
        csc[pos] = (int)(p & 0x1FFFFu);
    }
}

// ---------------------------------------------------------------- MFMA GEMMs
// mfma_f32_16x16x32_f16 layouts (gfx950):
//   A: lane l holds A[row = l&15][k = (l>>4)*8 + j], j=0..7
//   B: lane l holds B[k = (l>>4)*8 + j][col = l&15]
//   C: lane l, reg r -> row = (l>>4)*4 + r, col = l&15
// Block = 4 waves x 16 rows = 64 rows. W^T in LDS, XOR-swizzled by (col&7).

__global__ __launch_bounds__(256) void gemm1_mfma(const float* __restrict__ X,
                                                  const __half* __restrict__ Wt,  // [128][128] f16
                                                  const float* __restrict__ dinv,
                                                  __half* __restrict__ H, int nrows) {
    __shared__ half8 wt[2048];  // 32 KB
    const int t = threadIdx.x;

    const half8* Wg = reinterpret_cast<const half8*>(Wt);
    for (int i = t; i < 2048; i += 256) {
        int col = i >> 4, kc = i & 15;
        wt[(col << 4) | (kc ^ (col & 7))] = Wg[i];
    }

    const int wid = t >> 6, lane = t & 63;
    const int li = lane & 15, kq = lane >> 4;
    const int rbase = blockIdx.x * 64 + wid * 16;
    int row = rbase + li;
    int rowc = min(row, nrows - 1);

    const f32x4* X4 = reinterpret_cast<const f32x4*>(X) + (size_t)rowc * 32;
    half8 a[4];
#pragma unroll
    for (int kk = 0; kk < 4; ++kk) {
        f32x4 lo = __builtin_nontemporal_load(&X4[kk * 8 + kq * 2]);
        f32x4 hi = __builtin_nontemporal_load(&X4[kk * 8 + kq * 2 + 1]);
        half8 v;
        v[0] = (_Float16)lo[0]; v[1] = (_Float16)lo[1];
        v[2] = (_Float16)lo[2]; v[3] = (_Float16)lo[3];
        v[4] = (_Float16)hi[0]; v[5] = (_Float16)hi[1];
        v[6] = (_Float16)hi[2]; v[7] = (_Float16)hi[3];
        a[kk] = v;
    }
    __syncthreads();

    f32x4 acc[8];
#pragma unroll
    for (int ct = 0; ct < 8; ++ct) acc[ct] = (f32x4){0.f, 0.f, 0.f, 0.f};

#pragma unroll
    for (int ct = 0; ct < 8; ++ct) {
        int col = ct * 16 + li;
        int cbase = col << 4, sw = col & 7;
#pragma unroll
        for (int kk = 0; kk < 4; ++kk) {
            half8 b = wt[cbase | ((kk * 4 + kq) ^ sw)];
            acc[ct] = __builtin_amdgcn_mfma_f32_16x16x32_f16(a[kk], b, acc[ct], 0, 0, 0);
        }
    }

    const int r0 = rbase + kq * 4;
#pragma unroll
    for (int r = 0; r < 4; ++r) {
        int rr = r0 + r;
        if (rr < nrows) {
            float s = dinv[rr];
            __half* orow = H + (size_t)rr * 128;
#pragma unroll
            for (int ct = 0; ct < 8; ++ct)
                orow[ct * 16 + li] = __float2half(acc[ct][r] * s);
        }
    }
}

__global__ __launch_bounds__(256) void gemm2_mfma(const __half* __restrict__ Xh,
                                                  const __half* __restrict__ Wt,  // [64][128] f16
                                                  const float* __restrict__ dinv,
                                                  __half* __restrict__ H, int nrows) {
    __shared__ half8 wt[1024];  // 16 KB
    const int t = threadIdx.x;

    const half8* Wg = reinterpret_cast<const half8*>(Wt);
    for (int i = t; i < 1024; i += 256) {
        int col = i >> 4, kc = i & 15;
        wt[(col << 4) | (kc ^ (col & 7))] = Wg[i];
    }

    const int wid = t >> 6, lane = t & 63;
    const int li = lane & 15, kq = lane >> 4;
    const int rbase = blockIdx.x * 64 + wid * 16;
    int row = rbase + li;
    int rowc = min(row, nrows - 1);

    const half8* A8 = reinterpret_cast<const half8*>(Xh) + (size_t)rowc * 16;
    half8 a[4];
#pragma unroll
    for (int kk = 0; kk < 4; ++kk) a[kk] = A8[kk * 4 + kq];
    __syncthreads();

    f32x4 acc[4];
#pragma unroll
    for (int ct = 0; ct < 4; ++ct) acc[ct] = (f32x4){0.f, 0.f, 0.f, 0.f};

#pragma unroll
    for (int ct = 0; ct < 4; ++ct) {
        int col = ct * 16 + li;
        int cbase = col << 4, sw = col & 7;
#pragma unroll
        for (int kk = 0; kk < 4; ++kk) {
            half8 b = wt[cbase | ((kk * 4 + kq) ^ sw)];
            acc[ct] = __builtin_amdgcn_mfma_f32_16x16x32_f16(a[kk], b, acc[ct], 0, 0, 0);
        }
    }

    const int r0 = rbase + kq * 4;
#pragma unroll
    for (int r = 0; r < 4; ++r) {
        int rr = r0 + r;
        if (rr < nrows) {
            float s = dinv[rr];
            __half* orow = H + (size_t)rr * 64;
#pragma unroll
            for (int ct = 0; ct < 4; ++ct)
                orow[ct * 16 + li] = __float2half(acc[ct][r] * s);
        }
    }
}

// ---------------------------------------------------------------- aggregation
// One wave per node; lanes 0-31 gather edge e, lanes 32-63 edge e+1.
// Scalar index loads via readfirstlane'd offsets; 32-bit saddr+voffset
// gathers; 8 edges (4 loads/lane) per main-loop iteration (round-6 form).

__global__ __launch_bounds__(256) void k_agg1(const __half* __restrict__ h,
                                              const int* __restrict__ offs,
                                              const int* __restrict__ csc,
                                              const float* __restrict__ dinv,
                                              const float* __restrict__ bias,
                                              __half* __restrict__ out, int n) {
    int node = (blockIdx.x * 256 + threadIdx.x) >> 6;
    if (node >= n) return;
    int lane = threadIdx.x & 63;
    int g = lane >> 5, li = lane & 31;            // li covers cols 4li..4li+3
    const char* hb = reinterpret_cast<const char*>(h);  // row = 256 B
    const unsigned loff = (unsigned)li << 3;
    int start = __builtin_amdgcn_readfirstlane(offs[node]);
    int end   = __builtin_amdgcn_readfirstlane(offs[node + 1]);
    float4 acc = make_float4(0.f, 0.f, 0.f, 0.f);

    int e = start;
    int emain = start + ((end - start) & ~7);
    for (; e < emain; e += 8) {
        int a0 = csc[e],     a1 = csc[e + 1], a2 = csc[e + 2], a3 = csc[e + 3];
        int a4 = csc[e + 4], a5 = csc[e + 5], a6 = csc[e + 6], a7 = csc[e + 7];
        unsigned o0 = (((unsigned)(g ? a1 : a0)) << 8) | loff;
        unsigned o1 = (((unsigned)(g ? a3 : a2)) << 8) | loff;
        unsigned o2 = (((unsigned)(g ? a5 : a4)) << 8) | loff;
        unsigned o3 = (((unsigned)(g ? a7 : a6)) << 8) | loff;
        uint2 v0 = ld8(hb, o0);
        uint2 v1 = ld8(hb, o1);
        uint2 v2 = ld8(hb, o2);
        uint2 v3 = ld8(hb, o3);
        acc8(acc, v0); acc8(acc, v1); acc8(acc, v2); acc8(acc, v3);
    }
    for (; e < end; e += 2) {
        int sa = csc[e];
        int sb = (e + 1 < end) ? csc[e + 1] : sa;
        unsigned o = (((unsigned)(g ? sb : sa)) << 8) | loff;
        uint2 v = ld8(hb, o);
        if (g && (e + 1 >= end)) { v.x = 0u; v.y = 0u; }
        acc8(acc, v);
    }
    acc.x += __shfl_xor(acc.x, 32);
    acc.y += __shfl_xor(acc.y, 32);
    acc.z += __shfl_xor(acc.z, 32);
    acc.w += __shfl_xor(acc.w, 32);
    uint2 vs = ld8(hb, (((unsigned)node) << 8) | loff);  // self loop
    acc8(acc, vs);
    float di = dinv[node];
    float4 bb = reinterpret_cast<const float4*>(bias)[li];
    float ox = fmaxf(fmaf(acc.x, di, bb.x), 0.f);
    float oy = fmaxf(fmaf(acc.y, di, bb.y), 0.f);
    float oz = fmaxf(fmaf(acc.z, di, bb.z), 0.f);
    float ow = fmaxf(fmaf(acc.w, di, bb.w), 0.f);
    if (g == 0)
        reinterpret_cast<uint2*>(out)[(size_t)node * 32 + li] =
            make_uint2(pack_half2(ox, oy), pack_half2(oz, ow));
}

__global__ __launch_bounds__(256) void k_agg2(const __half* __restrict__ h,
                                              const int* __restrict__ offs,
                                              const int* __restrict__ csc,
                                              const float* __restrict__ dinv,
                                              const float* __restrict__ bias,
                                              float* __restrict__ out, int n) {
    int node = (blockIdx.x * 256 + threadIdx.x) >> 6;
    if (node >= n) return;
    int lane = threadIdx.x & 63;
    int g = lane >> 5, li = lane & 31;            // li covers cols 2li..2li+1
    const char* hb = reinterpret_cast<const char*>(h);  // row = 128 B
    const unsigned loff = (unsigned)li << 2;
    int start = __builtin_amdgcn_readfirstlane(offs[node]);
    int end   = __builtin_amdgcn_readfirstlane(offs[node + 1]);
    float2 acc = make_float2(0.f, 0.f);

    int e = start;
    int emain = start + ((end - start) & ~7);
    for (; e < emain; e += 8) {
        int a0 = csc[e],     a1 = csc[e + 1], a2 = csc[e + 2], a3 = csc[e + 3];
        int a4 = csc[e + 4], a5 = csc[e + 5], a6 = csc[e + 6], a7 = csc[e + 7];
        unsigned o0 = (((unsigned)(g ? a1 : a0)) << 7) | loff;
        unsigned o1 = (((unsigned)(g ? a3 : a2)) << 7) | loff;
        unsigned o2 = (((unsigned)(g ? a5 : a4)) << 7) | loff;
        unsigned o3 = (((unsigned)(g ? a7 : a6)) << 7) | loff;
        unsigned v0 = ld4(hb, o0);
        unsigned v1 = ld4(hb, o1);
        unsigned v2 = ld4(hb, o2);
        unsigned v3 = ld4(hb, o3);
        acc4(acc, v0); acc4(acc, v1); acc4(acc, v2); acc4(acc, v3);
    }
    for (; e < end; e += 2) {
        int sa = csc[e];
        int sb = (e + 1 < end) ? csc[e + 1] : sa;
        unsigned o = (((unsigned)(g ? sb : sa)) << 7) | loff;
        unsigned v = ld4(hb, o);
        if (g && (e + 1 >= end)) v = 0u;
        acc4(acc, v);
    }
    acc.x += __shfl_xor(acc.x, 32);
    acc.y += __shfl_xor(acc.y, 32);
    acc4(acc, ld4(hb, (((unsigned)node) << 7) | loff));  // self loop
    float di = dinv[node];
    float2 bb = reinterpret_cast<const float2*>(bias)[li];
    if (g == 0)
        reinterpret_cast<float2*>(out)[(size_t)node * 32 + li] =
            make_float2(fmaf(acc.x, di, bb.x), fmaf(acc.y, di, bb.y));
}

// ---------------------------------------------------------------- launch

extern "C" void kernel_launch(void* const* d_in, const int* in_sizes, int n_in,
                              void* d_out, int out_size, void* d_ws, size_t ws_size,
                              hipStream_t stream) {
    const float* x  = (const float*)d_in[0];
    const int*   ei = (const int*)d_in[1];
    const float* W1 = (const float*)d_in[2];
    const float* b1 = (const float*)d_in[3];
    const float* W2 = (const float*)d_in[4];
    const float* b2 = (const float*)d_in[5];
    float* out = (float*)d_out;

    const int n = in_sizes[0] / 128;   // 100000 (< 2^17: packed pairs valid)
    const int E = in_sizes[1] / 2;     // 1600000
    const int* src = ei;
    const int* dst = ei + E;
    const int NB = (n + BNODES - 1) / BNODES;  // 98 buckets of 1024 nodes

    // workspace carving (256B aligned)
    char* p = (char*)d_ws;
    auto carve = [&](size_t bytes) -> void* {
        void* r = (void*)p;
        p += (bytes + 255) & ~(size_t)255;
        return r;
    };
    float* dinv    = (float*)carve((size_t)n * 4);
    int*   offs    = (int*)carve((size_t)(n + 1) * 4);
    int*   bcnt    = (int*)carve((size_t)(NB + 1) * 4);
    __half* Wt1h   = (__half*)carve(16384 * 2);
    __half* Wt2h   = (__half*)carve(8192 * 2);
    int*   csc     = (int*)carve((size_t)E * 4);
    __half* h1     = (__half*)carve((size_t)n * 128 * 2);   // 25.6 MB
    __half* out1   = (__half*)carve((size_t)n * 128 * 2);   // 25.6 MB
    unsigned* pairs = (unsigned*)h1;  // NB*CAP*4 = 12.85 MB <= 25.6; dead before gemm1
    __half* h2     = h1;              // h1 dead after layer-1 aggregation

    const int gmm  = (n + 63) / 64;       // MFMA gemm blocks (64 rows each)
    const int gagg = (n + 3) / 4;
    const int GB   = 512;                 // bucket-pass blocks
    const int epb  = (E + GB - 1) / GB;   // edges per block (3125)

    // ---- init: weight convert+transpose + zero bcnt ----
    k_wconv<<<96, 256, 0, stream>>>(W1, W2, Wt1h, Wt2h, bcnt, NB + 1);

    // ---- CSC build (fixed-stride bucketed counting sort by dst) ----
    k_bscatter2<<<GB, 256, 0, stream>>>(src, dst, E, bcnt, pairs, NB, epb);
    k_bfinal2<<<NB, 256, 0, stream>>>(pairs, bcnt, dinv, offs, csc, n, E, NB);

    // ---- layer 1: h1 = f16((x @ W1) * dinv) ; out1 = f16(relu(agg*dinv + b1)) ----
    gemm1_mfma<<<gmm, 256, 0, stream>>>(x, Wt1h, dinv, h1, n);
    k_agg1<<<gagg, 256, 0, stream>>>(h1, offs, csc, dinv, b1, out1, n);

    // ---- layer 2: h2 = f16((out1 @ W2) * dinv) ; out = agg*dinv + b2 ----
    gemm2_mfma<<<gmm, 256, 0, stream>>>(out1, Wt2h, dinv, h2, n);
    k_agg2<<<gagg, 256, 0, stream>>>(h2, offs, csc, dinv, b2, out, n);
}